// Round 11
// baseline (344.301 us; speedup 1.0000x reference)
//
#include <hip/hip_runtime.h>
#include <hip/hip_bf16.h>
#include <cstdint>

// Problem constants (B=2, T=2048, NH=16, HD=128, VD=256)
// KD=2048, VDIM=4096, proj cols: [0,2048)=q, [2048,4096)=k, [4096,8192)=v,
// [8192,8208)=g, [8208,8224)=beta.
//
// Chunked WY delta rule: per chunk of C=64 (per seq=b*16+n):
//   G_t = prod g, L_t = cumsum log g
//   A[s,r] = b_s exp(L_s-L_r)(k_s.k_r)  (r<s)       N = -A
//   T = (I+A)^{-1} = Prod_{j=0..5}(I+N^{2^j})       (nilpotent Neumann)
//   P[t,s] = exp(L_t-L_s)(q_t.k_s)  (s<=t)
//   M = K S0^T ; Mq = Q S0^T
//   U = T (diag(b)V - diag(bG) M)
//   O = diag(G) Mq + P U
//   S_C = G_C S0 + U^T diag(G_C/G_s) K
//
// LDS swizzle convention (G4 fix; both-sides-or-neither, rule 21):
//   128-u16-row tile: elem (r,c) at r*128 + (((c>>3)^(r&7))<<3) + (c&7)
//   64-u16-row tile:  elem (r,c) at r*64  + (((c>>3)^(r&7))<<3) + (c&7)
//   32-u16-row tile:  elem (r,c) at r*32  + (((c>>3)^((r>>2)&3))<<3) + (c&7)
//   gll16-staged tiles keep LINEAR dest; inverse permutation applied on the
//   per-lane GLOBAL source address. VALU-written tiles swizzle the address.
//
// GEMM note (r9 post-mortem): controlled experiments showed the GEMM's
// ~155us is set by its 8-barrier lockstep skeleton, NOT by bank conflicts
// (1.26e7 vs 0: neutral), L2 over-fetch (276 vs 99MB: neutral), or read
// balance (r2/r9). Keeping the best-measured r1-skeleton variant.

typedef __attribute__((ext_vector_type(8))) short short8;
typedef __attribute__((ext_vector_type(4))) float f32x4;
typedef unsigned short u16;

using as1_void = __attribute__((address_space(1))) void;
using as3_void = __attribute__((address_space(3))) void;

__device__ __forceinline__ void gll16(const void* g, void* l) {
  // async global->LDS, 16B/lane; LDS dest = wave-uniform base + lane*16
  __builtin_amdgcn_global_load_lds((const as1_void*)g, (as3_void*)l, 16, 0, 0);
}

__device__ __forceinline__ u16 bf16_rne(float f) {
  union { float f; uint32_t u; } x; x.f = f;
  uint32_t u = x.u;
  return (u16)((u + 0x7fffu + ((u >> 16) & 1u)) >> 16);
}
__device__ __forceinline__ float bf2f(u16 v) {
  union { uint32_t u; float f; } x; x.u = (uint32_t)v << 16;
  return x.f;
}

// lgkm-only barrier: LDS producer->consumer sync without draining vmcnt
#define LGKM_BAR() do {                                      \
    asm volatile("s_waitcnt lgkmcnt(0)" ::: "memory");       \
    __builtin_amdgcn_s_barrier();                            \
    __builtin_amdgcn_sched_barrier(0);                       \
  } while (0)

#define SCHED_FENCE() __builtin_amdgcn_sched_barrier(0)
#define HW_BAR() __builtin_amdgcn_s_barrier()
#define LGKM0() asm volatile("s_waitcnt lgkmcnt(0)" ::: "memory")
#define VMCNT(n) asm volatile("s_waitcnt vmcnt(" #n ")" ::: "memory")
#define PRIO_HI() __builtin_amdgcn_s_setprio(1)
#define PRIO_LO() __builtin_amdgcn_s_setprio(0)

// ---------------- fused: W fp32->bf16 cvt  ||  gate projection ----------
// Independent workloads (cvt: HBM-bound; gate: L2/VALU-bound) run in one
// launch: blocks [0,256) = gate (4 rows/wave), blocks [256,16640) = cvt.
__global__ __launch_bounds__(256, 1) void prep_inputs(const float* __restrict__ x,
                                                      const float* __restrict__ W,
                                                      float* __restrict__ gbuf,
                                                      u16* __restrict__ xb,
                                                      u16* __restrict__ Wb) {
  if (blockIdx.x >= 256) {
    // ---- cvt path: W rows 0..8191 -> bf16 (4 floats/thread) ----
    int i = (blockIdx.x - 256) * 256 + threadIdx.x;  // < 4194304
    float4 v = ((const float4*)W)[i];
    ushort4 o;
    o.x = bf16_rne(v.x); o.y = bf16_rne(v.y);
    o.z = bf16_rne(v.z); o.w = bf16_rne(v.w);
    ((ushort4*)Wb)[i] = o;
    return;
  }
  // ---- gate path: 4 rows per wave; also emits bf16 x ----
  const int w = threadIdx.x >> 6, lane = threadIdx.x & 63;
  const int r0 = (blockIdx.x * 4 + w) * 4;  // 4 consecutive rows per wave
  const float* xr = x + (size_t)r0 * 2048 + lane * 32;
  float4 xv[4][8];
#pragma unroll
  for (int i = 0; i < 4; ++i)
#pragma unroll
    for (int j = 0; j < 8; ++j)
      xv[i][j] = ((const float4*)(xr + (size_t)i * 2048))[j];
  // bf16 x emit
#pragma unroll
  for (int i = 0; i < 4; ++i) {
    u16* xrow = xb + (size_t)(r0 + i) * 2048 + lane * 32;
#pragma unroll
    for (int j = 0; j < 8; ++j) {
      ushort4 o;
      o.x = bf16_rne(xv[i][j].x); o.y = bf16_rne(xv[i][j].y);
      o.z = bf16_rne(xv[i][j].z); o.w = bf16_rne(xv[i][j].w);
      ((ushort4*)xrow)[j] = o;
    }
  }
  for (int col = 0; col < 32; ++col) {
    const float* wp = W + (size_t)(8192 + col) * 2048 + lane * 32;
    float4 wv[8];
#pragma unroll
    for (int j = 0; j < 8; ++j) wv[j] = ((const float4*)wp)[j];
    float d[4] = {0.f, 0.f, 0.f, 0.f};
#pragma unroll
    for (int i = 0; i < 4; ++i)
#pragma unroll
      for (int j = 0; j < 8; ++j)
        d[i] += xv[i][j].x * wv[j].x + xv[i][j].y * wv[j].y +
                xv[i][j].z * wv[j].z + xv[i][j].w * wv[j].w;
#pragma unroll
    for (int i = 0; i < 4; ++i) {
      d[i] += __shfl_xor(d[i], 1);  d[i] += __shfl_xor(d[i], 2);
      d[i] += __shfl_xor(d[i], 4);  d[i] += __shfl_xor(d[i], 8);
      d[i] += __shfl_xor(d[i], 16); d[i] += __shfl_xor(d[i], 32);
    }
    if (lane == 0) {
#pragma unroll
      for (int i = 0; i < 4; ++i) {
        int rv = r0 + i, b = rv >> 11, t = rv & 2047;
        float s = 1.f / (1.f + __expf(-d[i]));
        gbuf[((size_t)(b * 16 + (col & 15)) * 2048 + t) * 2 + (col >> 4)] = s;
      }
    }
  }
}

// ---------------- 256^2 8-phase bf16 MFMA GEMM + fused q/k l2norm ----------
// (r8-measured version: r1 skeleton + st-style swizzle + XCD-bijective map)
__global__ __launch_bounds__(512, 2) void gemm_bf16_btn(const u16* __restrict__ A,
                                                        const u16* __restrict__ B,
                                                        u16* __restrict__ qb,
                                                        u16* __restrict__ kb,
                                                        u16* __restrict__ vb) {
  __shared__ __align__(16) u16 As[2][16384];
  __shared__ __align__(16) u16 Bs[2][16384];
  __shared__ float nrm[2][4][128];  // [wr][wc][row] partial sums (epilogue)

  const int tid = threadIdx.x;
  const int wid = tid >> 6, lane = tid & 63;
  const int lr = lane & 15, lk = lane >> 4;
  const int wr = wid >> 2, wc = wid & 3;

  // XCD-bijective swizzle: 512 wg, 8 XCDs, 64 wg chunks = 2 bm x 32 bn
  const int wg = ((blockIdx.x & 7) << 6) | (blockIdx.x >> 3);
  const int bm = wg >> 5, bn = wg & 31;

  const int e8s = (tid & 7) ^ (((tid >> 3) & 1) << 2) ^ (((tid >> 5) & 1) << 1);
  const int srow = tid >> 3;  // 0..63 within one 8KB call
  const u16* Agb = A + (size_t)(bm * 256 + srow) * 2048 + e8s * 8;
  const u16* Bgb = B + (size_t)(bn * 256 + srow) * 2048 + e8s * 8;

  const int kkx = lr & 1;
  const int lkp = lk ^ (((lr >> 2) & 1) << 1);
  const int aOff0 = (wr * 128 + lr) * 64 + kkx * 32 + lkp * 8;
  const int aOff1 = (wr * 128 + lr) * 64 + (1 ^ kkx) * 32 + lkp * 8;
  const int bOff0 = (wc * 64 + lr) * 64 + kkx * 32 + lkp * 8;
  const int bOff1 = (wc * 64 + lr) * 64 + (1 ^ kkx) * 32 + lkp * 8;

  auto stageA = [&](int bf, int kt, int h) {
    const u16* s = Agb + (size_t)(h * 128) * 2048 + kt * 64;
    u16* d = &As[bf][h * 8192 + wid * 512];
    gll16(s, d);
    gll16(s + (size_t)64 * 2048, d + 4096);
  };
  auto stageB = [&](int bf, int kt, int h) {
    const u16* s = Bgb + (size_t)(h * 128) * 2048 + kt * 64;
    u16* d = &Bs[bf][h * 8192 + wid * 512];
    gll16(s, d);
    gll16(s + (size_t)64 * 2048, d + 4096);
  };

  f32x4 acc[8][4] = {};

  stageA(0, 0, 0); stageA(0, 0, 1);
  stageB(0, 0, 0); stageB(0, 0, 1);
  stageA(1, 1, 0); stageA(1, 1, 1);
  stageB(1, 1, 0);
  VMCNT(6);
  SCHED_FENCE();
  HW_BAR();

#define QUAD(M0, N0)                                                          \
  do {                                                                        \
    __builtin_amdgcn_s_setprio(1);                                            \
    _Pragma("unroll")                                                         \
    for (int m_ = 0; m_ < 4; ++m_)                                            \
      _Pragma("unroll")                                                       \
      for (int n_ = 0; n_ < 2; ++n_) {                                        \
        acc[M0 + m_][N0 + n_] = __builtin_amdgcn_mfma_f32_16x16x32_bf16(      \
            a[M0 + m_][0], b[N0 + n_][0], acc[M0 + m_][N0 + n_], 0, 0, 0);    \
        acc[M0 + m_][N0 + n_] = __builtin_amdgcn_mfma_f32_16x16x32_bf16(      \
            a[M0 + m_][1], b[N0 + n_][1], acc[M0 + m_][N0 + n_], 0, 0, 0);    \
      }                                                                       \
    __builtin_amdgcn_s_setprio(0);                                            \
  } while (0)

  for (int kt = 0; kt < 32; ++kt) {
    const int bf = kt & 1;
    const u16* pA0 = &As[bf][aOff0];
    const u16* pA1 = &As[bf][aOff1];
    const u16* pB0 = &Bs[bf][bOff0];
    const u16* pB1 = &Bs[bf][bOff1];
    short8 a[8][2], b[4][2];

#pragma unroll
    for (int m = 0; m < 8; ++m) {
      a[m][0] = *(const short8*)(pA0 + m * 1024);
      a[m][1] = *(const short8*)(pA1 + m * 1024);
    }
#pragma unroll
    for (int n = 0; n < 2; ++n) {
      b[n][0] = *(const short8*)(pB0 + n * 1024);
      b[n][1] = *(const short8*)(pB1 + n * 1024);
    }
    SCHED_FENCE();
    if (kt < 31) stageB((kt + 1) & 1, kt + 1, 1);
    SCHED_FENCE(); HW_BAR(); LGKM0(); SCHED_FENCE();
    QUAD(0, 0);
    SCHED_FENCE(); HW_BAR();

#pragma unroll
    for (int n = 2; n < 4; ++n) {
      b[n][0] = *(const short8*)(pB0 + n * 1024);
      b[n][1] = *(const short8*)(pB1 + n * 1024);
    }
    SCHED_FENCE();
    if (kt < 30) stageA(bf, kt + 2, 0);
    SCHED_FENCE(); HW_BAR(); LGKM0(); SCHED_FENCE();
    QUAD(0, 2);
    SCHED_FENCE(); HW_BAR();

    if (kt < 30) stageA(bf, kt + 2, 1);
    SCHED_FENCE(); HW_BAR(); SCHED_FENCE();
    QUAD(4, 0);
    SCHED_FENCE(); HW_BAR();

    if (kt < 30) stageB(bf, kt + 2, 0);
    SCHED_FENCE(); HW_BAR(); SCHED_FENCE();
    QUAD(4, 2);
    SCHED_FENCE();
    if (kt < 30) { VMCNT(6); } else if (kt == 30) { VMCNT(0); }
    SCHED_FENCE(); HW_BAR();
  }
#undef QUAD

  // ---- epilogue: C/D layout col = lane&15, row = (lane>>4)*4 + reg ----
  if (bn < 16) {
    // q/k block: fused l2norm (same bf16-rounded values as two-pass version).
#pragma unroll
    for (int m = 0; m < 8; ++m)
#pragma unroll
      for (int r = 0; r < 4; ++r) {
        float s = 0.f;
#pragma unroll
        for (int nn = 0; nn < 4; ++nn) {
          float v = bf2f(bf16_rne(acc[m][nn][r]));
          s += v * v;
        }
        s += __shfl_xor(s, 1); s += __shfl_xor(s, 2);
        s += __shfl_xor(s, 4); s += __shfl_xor(s, 8);
        if (lr == 0) nrm[wr][wc][m * 16 + lk * 4 + r] = s;
      }
    __syncthreads();
#pragma unroll
    for (int m = 0; m < 8; ++m)
#pragma unroll
      for (int r = 0; r < 4; ++r) {
        int rloc = m * 16 + lk * 4 + r;
        float ss = nrm[wr][wc][rloc] + nrm[wr][wc ^ 1][rloc];
        float sc = 1.f / fmaxf(sqrtf(ss), 1e-12f);
        int row = bm * 256 + wr * 128 + rloc;
        int bb = row >> 11, tt = row & 2047;
#pragma unroll
        for (int nn = 0; nn < 4; ++nn) {
          int col = bn * 256 + wc * 64 + nn * 16 + lr;
          int head = (col >> 7) & 15;
          int h = col & 127;
          u16 val = bf16_rne(bf2f(bf16_rne(acc[m][nn][r])) * sc);
          u16* dst = (col < 2048) ? qb : kb;
          dst[((size_t)(bb * 16 + head) * 2048 + tt) * 128 + h] = val;
        }
      }
  } else {
    // v block: plain store
#pragma unroll
    for (int m = 0; m < 8; ++m)
#pragma unroll
      for (int nn = 0; nn < 4; ++nn)
#pragma unroll
        for (int r = 0; r < 4; ++r) {
          int row = bm * 256 + wr * 128 + m * 16 + lk * 4 + r;
          int col = bn * 256 + wc * 64 + nn * 16 + lr;
          int bb = row >> 11, tt = row & 2047;
          u16 val = bf16_rne(acc[m][nn][r]);
          int vh = col - 4096;
          vb[((size_t)(bb * 16 + (vh >> 8)) * 2048 + tt) * 256 + (vh & 255)] = val;
        }
  }
}

// ---------------- chunk_prep: per (seq,chunk) T,P,gatepack (swizzled LDS) ---
// Staging spread over all 4 waves (w0/w2: K halves, w1/w3: Q halves, w2: gl)
__global__ __launch_bounds__(256) void chunk_prep(const u16* __restrict__ qb,
                                                  const u16* __restrict__ kb,
                                                  const float* __restrict__ gbuf,
                                                  float* __restrict__ gp,
                                                  u16* __restrict__ Tm,
                                                  u16* __restrict__ Pm) {
  __shared__ u16 Kc[64 * 128];
  __shared__ u16 Qc[64 * 128];
  __shared__ u16 Nn[64 * 64];
  __shared__ u16 NT[64 * 64];
  __shared__ u16 Tt[64 * 64];
  __shared__ u16 TTt[64 * 64];
  __shared__ float gl[256];
  __shared__ float Lw[64];
  __shared__ float bw[64];

  const int bid = blockIdx.x;
  const int seq = bid >> 5, c = bid & 31;
  const int t0 = c * 64;
  const int tid = threadIdx.x;
  const int w = tid >> 6, lane = tid & 63;
  const int lr = lane & 15, lk = lane >> 4;
  const int lr7 = lr & 7;

  {
    const int rowo = lane >> 4;
    const int c8e = (lane & 15) ^ rowo;
    const int c8o = (lane & 15) ^ (4 | rowo);
    if ((w & 1) == 0) {  // w0: Kc[0..8), w2: Kc[8..16) + gl
      const int i0 = (w == 0) ? 0 : 8;
      const u16* se = kb + ((size_t)seq * 2048 + t0 + rowo) * 128 + c8e * 8;
      const u16* so = kb + ((size_t)seq * 2048 + t0 + rowo) * 128 + c8o * 8;
#pragma unroll
      for (int i = 0; i < 8; ++i) {
        const int ii = i0 + i;
        gll16(((ii & 1) ? so : se) + (size_t)ii * 512, &Kc[ii * 512]);
      }
      if (w == 2) gll16(gbuf + (size_t)seq * 4096 + c * 128 + lane * 4, &gl[0]);
    } else {             // w1: Qc[0..8), w3: Qc[8..16)
      const int i0 = (w == 1) ? 0 : 8;
      const u16* se = qb + ((size_t)seq * 2048 + t0 + rowo) * 128 + c8e * 8;
      const u16* so = qb + ((size_t)seq * 2048 + t0 + rowo) * 128 + c8o * 8;
#pragma unroll
      for (int i = 0; i < 8; ++i) {
        const int ii = i0 + i;
        gll16(((ii & 1) ? so : se) + (size_t)ii * 512, &Qc[ii * 512]);
      }
    }
  }
  __syncthreads();

  if (w == 0) {
    float g = gl[2 * lane], b = gl[2 * lane + 1];
    float lg = __logf(g);
#pragma unroll
    for (int d = 1; d < 64; d <<= 1) {
      float y = __shfl_up(lg, d);
      if (lane >= d) lg += y;
    }
    Lw[lane] = lg;
    bw[lane] = b;
    float G = __expf(lg);
    float L63 = __shfl(lg, 63);
    float wgt = __expf(L63 - lg);
    float* gpo = gp + ((size_t)seq * 32 + c) * 256;
    gpo[lane] = b;
    gpo[64 + lane] = b * G;
    gpo[128 + lane] = G;
    gpo[192 + lane] = wgt;
  }
  __syncthreads();

  f32x4 kkacc[4] = {}, qkacc[4] = {};
#pragma unroll
  for (int ct = 0; ct < 4; ++ct)
#pragma unroll
    for (int k0 = 0; k0 < 4; ++k0) {
      const int sl = ((k0 * 4 + lk) ^ lr7) << 3;
      short8 bfr = *(const short8*)&Kc[(ct * 16 + lr) * 128 + sl];
      short8 afk = *(const short8*)&Kc[(w * 16 + lr) * 128 + sl];
      short8 afq = *(const short8*)&Qc[(w * 16 + lr) * 128 + sl];
      kkacc[ct] = __builtin_amdgcn_mfma_f32_16x16x32_bf16(afk, bfr, kkacc[ct], 0, 0, 0);
      qkacc[ct] = __builtin_amdgcn_mfma_f32_16x16x32_bf16(afq, bfr, qkacc[ct], 0, 0, 0);
    }
  u16* Pout = Pm + ((size_t)seq * 32 + c) * 4096;
#pragma unroll
  for (int ct = 0; ct < 4; ++ct)
#pragma unroll
    for (int r = 0; r < 4; ++r) {
      int s = w * 16 + lk * 4 + r;
      int cc = ct * 16 + lr;
      int iA = s * 64 + ((((ct * 2 + (lr >> 3)) ^ (s & 7)) << 3)) + lr7;
      int iB = cc * 64 + ((((s >> 3) ^ lr7) << 3)) + (s & 7);
      u16 nv = 0;
      if (cc < s)
        nv = bf16_rne(-(bw[s] * __expf(Lw[s] - Lw[cc]) * kkacc[ct][r]));
      Nn[iA] = nv;
      NT[iB] = nv;
      u16 tv = (cc == s) ? (u16)0x3F80 : nv;
      Tt[iA] = tv;
      TTt[iB] = tv;
      u16 pv = 0;
      if (cc <= s)
        pv = bf16_rne(__expf(Lw[s] - Lw[cc]) * qkacc[ct][r]);
      Pout[s * 64 + cc] = pv;
    }
  __syncthreads();

  u16* Tout = Tm + ((size_t)seq * 32 + c) * 4096;
#pragma unroll 1
  for (int j = 0; j < 5; ++j) {
    f32x4 acc2[4] = {};
#pragma unroll
    for (int ct = 0; ct < 4; ++ct)
#pragma unroll
      for (int k0 = 0; k0 < 2; ++k0) {
        const int sl = ((k0 * 4 + lk) ^ lr7) << 3;
        short8 af = *(const short8*)&Nn[(w * 16 + lr) * 64 + sl];
        short8 bfr = *(const short8*)&NT[(ct * 16 + lr) * 64 + sl];
        acc2[ct] = __builtin_amdgcn_mfma_f32_16x16x32_bf16(af, bfr, acc2[ct], 0, 0, 0);
      }
    __syncthreads();
#pragma unroll
    for (int ct = 0; ct < 4; ++ct)
#pragma unroll
      for (int r = 0; r < 4; ++r) {
        int s = w * 16 + lk * 4 + r, cc = ct * 16 + lr;
        int iA = s * 64 + ((((ct * 2 + (lr >> 3)) ^ (s & 7)) << 3)) + lr7;
        int iB = cc * 64 + ((((s >> 3) ^ lr7) << 3)) + (s & 7);
        u16 v = bf16_rne(acc2[ct][r]);
        Nn[iA] = v;
        NT[iB] = v;
      }
    __syncthreads();
    f32x4 acc3[4];
#pragma unroll
    for (int ct = 0; ct < 4; ++ct)
#pragma unroll
      for (int r = 0; r < 4; ++r) {
        int a = w * 16 + lk * 4 + r;
        acc3[ct][r] = bf2f(Tt[a * 64 + ((((ct * 2 + (lr >> 3)) ^ (a & 7)) << 3)) + lr7]);
      }
#pragma unroll
    for (int ct = 0; ct < 4; ++ct)
#pragma unroll
      for (int k0 = 0; k0 < 2; ++k0) {
        const int sl = ((k0 * 4 + lk) ^ lr7) << 3;
        short8 af = *(const short8*)&Nn[(w * 16 + lr) * 64 + sl];
        short8 bfr = *(const short8*)&TTt[(ct * 16 + lr) * 64 + sl];
        acc3[ct] = __builtin_amdgcn_mfma_f32_16x16x32_bf16(af, bfr, acc3[ct], 0, 0, 0);
      }
    __syncthreads();
    if (j < 4) {
#pragma unroll
      for (int ct = 0; ct < 4; ++ct)
#pragma unroll
        for (int r = 0; r < 4; ++r) {
          int s = w * 16 + lk * 4 + r, cc = ct * 16 + lr;
          int iA = s * 64 + ((((ct * 2 + (lr >> 3)) ^ (s & 7)) << 3)) + lr7;
          int iB = cc * 64 + ((((s >> 3) ^ lr7) << 3)) + (s & 7);
          u16 v = bf16_rne(acc3[ct][r]);
          Tt[iA] = v;
          TTt[iB] = v;
        }
      __syncthreads();
    } else {
#pragma unroll
      for (int ct = 0; ct < 4; ++ct)
#pragma unroll
        for (int r = 0; r < 4; ++r) {
          int s = w * 16 + lk * 4 + r, cc = ct * 16 + lr;
          Tout[s * 64 + cc] = bf16_rne(acc3[ct][r]);
        }
    }
  }
}

// ---------------- chunk_scan: serial over 32 chunks, MFMA, 8 waves ----------
// 512 thr (r6 structure + KTw in phase C + T5 setprio around MFMA clusters:
// phases B/C/D have wave role-diversity -> the scheduler has something to
// arbitrate, unlike the lockstep-null case m190).
__global__ __launch_bounds__(512) void chunk_scan(const u16* __restrict__ qb,
                                                  const u16* __restrict__ kb,
                                                  const u16* __restrict__ vb,
                                                  const float* __restrict__ gp,
                                                  const u16* __restrict__ Tm,
                                                  const u16* __restrict__ Pm,
                                                  const float* __restrict__ st0,
                                                  float* __restrict__ out) {
  __shared__ u16 Kc[2][64 * 128];
  __shared__ u16 Qc[2][64 * 128];
  __shared__ u16 Vc[2][64 * 32];
  __shared__ u16 Tc[2][64 * 64];
  __shared__ u16 Pc[2][64 * 64];
  __shared__ float gpl[2][256];
  __shared__ u16 KTw[128 * 64];
  __shared__ u16 Sb[32 * 128];
  __shared__ u16 RT[32 * 64];
  __shared__ u16 UT[32 * 64];

  const int bid = blockIdx.x;
  const int shard = bid >> 5, seq = bid & 31;
  const int vs0 = shard * 32;
  const int b = seq >> 4, n = seq & 15;
  const int tid = threadIdx.x;
  const int w = tid >> 6, lane = tid & 63;
  const int lr = lane & 15, lk = lane >> 4;
  const int lr7 = lr & 7;
  const int w3 = w & 3;
  const int vt = w & 1, hgb = (w >> 1) * 2;  // state: 2 h-tiles per wave

  const u16* kbase = kb + (size_t)seq * 2048 * 128;
  const u16* qbase = qb + (size_t)seq * 2048 * 128;
  const u16* vbase = vb + (size_t)seq * 2048 * 256 + vs0;
  const float* gpbase = gp + (size_t)seq * 32 * 256;
  const u16* Tbase = Tm + (size_t)seq * 32 * 4096;
  const u16* Pbase = Pm + (size_t)seq * 32 * 4096;

  // staging source pre-swizzle constants
  const int rowo = lane >> 4;
  const int c8e = (lane & 15) ^ rowo;          // even 4-row group (128-col tiles)
  const int c8o = (lane & 15) ^ (4 | rowo);    // odd 4-row group
  const int tp8 = (lane & 7) ^ (lane >> 3);    // T/P 64-col tiles (i-indep)
  const int vc8 = (lane & 3) ^ (lane >> 4);    // V 32-col tile (i-indep)

  auto stage = [&](int sb, int c) {
    const int t0 = c * 64;
    if (w == 0 || w == 4) {
      const int i0 = (w == 0) ? 0 : 8;
      const u16* se = kbase + (size_t)(t0 + rowo) * 128 + c8e * 8;
      const u16* so = kbase + (size_t)(t0 + rowo) * 128 + c8o * 8;
#pragma unroll
      for (int i = 0; i < 8; ++i) {
        const int ii = i0 + i;
        gll16(((ii & 1) ? so : se) + (size_t)ii * 512, &Kc[sb][ii * 512]);
      }
    } else if (w == 1 || w == 5) {
      const int i0 = (w == 1) ? 0 : 8;
      const u16* se = qbase + (size_t)(t0 + rowo) * 128 + c8e * 8;
      const u16* so = qbase + (size_t)(t0 + rowo) * 128 + c8o * 8;
#pragma unroll
      for (int i = 0; i < 8; ++i) {
        const int ii = i0 + i;
        gll16(((ii & 1) ? so : se) + (size_t)ii * 512, &Qc[sb][ii * 512]);
      }
    } else if (w == 2) {
      const u16* srcT = Tbase + (size_t)c * 4096 + (lane >> 3) * 64 + tp8 * 8;
#pragma unroll
      for (int i = 0; i < 8; ++i) gll16(srcT + (size_t)i * 512, &Tc[sb][i * 512]);
    } else if (w == 6) {
      const u16* srcP = Pbase + (size_t)c * 4096 + (lane >> 3) * 64 + tp8 * 8;
#pragma unroll
      for (int i = 0; i < 8; ++i) gll16(srcP + (size_t)i * 512, &Pc[sb][i * 512]);
    } else if (w == 3) {
      const u16* src = vbase + (size_t)(t0 + (lane >> 2)) * 256 + vc8 * 8;
#pragma unroll
      for (int i = 0; i < 4; ++i) gll16(src + (size_t)i * 4096, &Vc[sb][i * 512]);
    } else {  // w == 7
      gll16(gpbase + (size_t)c * 256 + lane * 4, &gpl[sb][0]);
    }
  };

  // state init: wave owns rows vt*16.. (v) x h-tiles hgb..hgb+1
  f32x4 s_acc[2];
  {
    const float* s0p = st0 + ((size_t)seq * 256 + vs0) * 128;
#pragma unroll
    for (int ht = 0; ht < 2; ++ht)
#pragma unroll
      for (int r = 0; r < 4; ++r)
        s_acc[ht][r] = s0p[(size_t)(vt * 16 + lk * 4 + r) * 128 + (hgb + ht) * 16 + lr];
  }
  stage(0, 0);
  __syncthreads();

  for (int c = 0; c < 32; ++c) {
    const int buf = c & 1;
    const int t0 = c * 64;

    // ---- phase A: prefetch next chunk; build Sb (bf16 state) ----
    stage(buf ^ 1, (c < 31) ? c + 1 : 31);
#pragma unroll
    for (int ht = 0; ht < 2; ++ht)
#pragma unroll
      for (int r = 0; r < 4; ++r) {
        int row = vt * 16 + lk * 4 + r;
        int c8 = (hgb + ht) * 2 + (lr >> 3);
        Sb[row * 128 + ((c8 ^ (row & 7)) << 3) + lr7] = bf16_rne(s_acc[ht][r]);
      }
    LGKM_BAR();

    // ---- phase B: waves 0-3: M = K Sb^T -> RT ; waves 4-7: Mq = Q Sb^T ----
    f32x4 mm_acc[2] = {};
    if (w < 4) {
      PRIO_HI();
#pragma unroll
      for (int ct = 0; ct < 2; ++ct)
#pragma unroll
        for (int k0 = 0; k0 < 4; ++k0) {
          const int sl = ((k0 * 4 + lk) ^ lr7) << 3;
          short8 bfr = *(const short8*)&Sb[(ct * 16 + lr) * 128 + sl];
          short8 afk = *(const short8*)&Kc[buf][(w3 * 16 + lr) * 128 + sl];
          mm_acc[ct] = __builtin_amdgcn_mfma_f32_16x16x32_bf16(afk, bfr, mm_acc[ct], 0, 0, 0);
        }
      PRIO_LO();
#pragma unroll
      for (int ct = 0; ct < 2; ++ct)
#pragma unroll
        for (int r = 0; r < 4; ++r) {
          int t = w3 * 16 + lk * 4 + r;
          int j2 = ct * 16 + lr;
          float bt = gpl[buf][t], bG = gpl[buf][64 + t];
          float vv = bf2f(Vc[buf][t * 32 + ((((ct * 2 + (lr >> 3)) ^ lk)) << 3) + lr7]);
          float rv = bt * vv - bG * mm_acc[ct][r];
          RT[j2 * 64 + (((t >> 3) ^ lr7) << 3) + (t & 7)] = bf16_rne(rv);
        }
    } else {
      PRIO_HI();
#pragma unroll
      for (int ct = 0; ct < 2; ++ct)
#pragma unroll
        for (int k0 = 0; k0 < 4; ++k0) {
          const int sl = ((k0 * 4 + lk) ^ lr7) << 3;
          short8 bfr = *(const short8*)&Sb[(ct * 16 + lr) * 128 + sl];
          short8 afq = *(const short8*)&Qc[buf][(w3 * 16 + lr) * 128 + sl];
          mm_acc[ct] = __builtin_amdgcn_mfma_f32_16x16x32_bf16(afq, bfr, mm_acc[ct], 0, 0, 0);
        }
      PRIO_LO();
    }
    LGKM_BAR();

    // ---- phase C: waves 0-3: U = T R -> UT ; waves 4-7: build KTw ----
    if (w < 4) {
      f32x4 u_acc[2] = {};
      PRIO_HI();
#pragma unroll
      for (int ct = 0; ct < 2; ++ct)
#pragma unroll
        for (int k0 = 0; k0 < 2; ++k0) {
          const int sl = ((k0 * 4 + lk) ^ lr7) << 3;
          short8 af = *(const short8*)&Tc[buf][(w3 * 16 + lr) * 64 + sl];
          short8 bfr = *(const short8*)&RT[(ct * 16 + lr) * 64 + sl];
          u_acc[ct] = __builtin_amdgcn_mfma_f32_16x16x32_bf16(af, bfr, u_acc[ct], 0, 0, 0);
        }
      PRIO_LO();
#pragma unroll
      for (int ct = 0; ct < 2; ++ct)
#pragma unroll
        for (int r = 0; r < 4; ++r) {
          int s2 = w3 * 16 + lk * 4 + r;
          int j2 = ct * 16 + lr;
          UT[j2 * 64 + (((s2 >> 3) ^ lr7) << 3) + (s2 & 7)] = bf16_rne(u_acc[ct][r]);
        }
    } else {
      // KTw[h][s] = (G_C/G_s) * K[s][h], swizzled 64-u16-row layout.
      const int s = (tid - 256) >> 2;  // 0..63
      const int cb0 = (tid & 3) * 4;   // col slots cb0..cb0+3 (h = slot*8+j)
      const float ws = gpl[buf][192 + s];
#pragma unroll
      for (int q = 0; q < 4; ++q) {
        const int cb = cb0 + q;
        short8 kv = *(const short8*)&Kc[buf][s * 128 + ((cb ^ (s & 7)) << 3)];
#pragma unroll
        for (int j = 0; j < 8; ++j) {
          int row = cb * 8 + j;
          KTw[row * 64 + (((s >> 3) ^ (j & 7)) << 3) + (s & 7)] =
              bf16_rne(ws * bf2f((u16)kv[j]));
        }
      }
    }
    LGKM_BAR();

    // ---- phase D: all: S = G_C S + U^T KTw ; waves 4-7: O -> out ----
    {
      const float Gc = gpl[buf][128 + 63];
#pragma unroll
      for (int ht = 0; ht < 2; ++ht) {
        s_acc[ht][0] *= Gc; s_acc[ht][1] *= Gc;
        s_acc[ht][2] *= Gc; s_acc[ht][3] *= Gc;
      }
      PRIO_HI();
#pragma unroll
      for (int ht = 0; ht < 2; ++ht)
#pragma unroll
        for (int k0 = 0; k0 < 2; ++k0) {
          const int sl = ((k0 * 4 + lk) ^ lr7) << 3;
          short8 af = *(const short8*)&UT[(vt * 16 + lr) * 64 + sl];
          short8 bfr = *(const short8*)&KTw[((hgb + ht) * 16 + lr) * 64 + sl];
          s_acc[ht] = __builtin_amdgcn_mfma_f32_16x16x32_bf16(af, bfr, s_acc[ht], 0, 0, 0);
        }
      PRIO_LO();
    }
    if (w >= 4) {
      f32x4 o_acc[2];
#pragma unroll
      for (int ct = 0; ct < 2; ++ct)
#pragma unroll
        for (int r = 0; r < 4; ++r) {
          int t = w3 * 16 + lk * 4 + r;
          o_acc[ct][r] = gpl[buf][128 + t] * mm_acc[ct][r];
        }
      PRIO_HI();
#pragma unroll
      for (int ct = 0; ct < 2; ++ct)
#pragma unroll
        for (int k0 = 0; k0 < 2; ++k0) {
          const int sl = ((k0 * 4 + lk) ^ lr7) << 3;
          short8 af = *(const short8*)&Pc[buf][(w3 * 16 + lr) * 64 + sl];
          short8 bfr = *(const short8*)&UT[(ct * 16 + lr) * 64 + sl];
          o_acc[ct] = __builtin_amdgcn_mfma_f32_16x16x32_bf16(af, bfr, o_acc[ct], 0, 0, 0);
        }
      PRIO_LO();
#pragma unroll
      for (int ct = 0; ct < 2; ++ct)
#pragma unroll
        for (int r = 0; r < 4; ++r) {
          int t = w3 * 16 + lk * 4 + r;
          int j2 = ct * 16 + lr;
          out[(((size_t)b * 2048 + t0 + t) * 16 + n) * 256 + vs0 + j2] = o_acc[ct][r];
        }
    }
    __syncthreads();  // drains vmcnt: next chunk staged; LDS reads done
  }
}

extern "C" void kernel_launch(void* const* d_in, const int* in_sizes, int n_in,
                              void* d_out, int out_size, void* d_ws, size_t ws_size,
                              hipStream_t stream) {
  const float* x = (const float*)d_in[0];    // [2,2048,2048]
  const float* W = (const float*)d_in[1];    // [8224,2048]
  const float* st0 = (const float*)d_in[2];  // [2,16,256,128] (zeros)
  float* out = (float*)d_out;                // [2,2048,16,256]
  char* ws = (char*)d_ws;

  u16* xb   = (u16*)ws;                        // 16 MB bf16 x
  u16* Wb   = (u16*)(ws + 16777216);           // 32 MB bf16 W
  u16* qb   = (u16*)(ws + 50331648);           // [32][2048][128] bf16 16MB
  u16* kb   = (u16*)(ws + 67108864);           // [32][2048][128] bf16 16MB
  u16* vb   = (u16*)(ws + 83886080);           // [32][2048][256] bf16 32MB
  float* gb = (float*)(ws + 117440512);        // [32][2048][2] f32 512KB (+slack)
  float* gp = (float*)(ws + 123731968);        // [32][32][4][64] f32 1MB
  u16* Tm   = (u16*)(ws + 125829120);          // [32][32][64][64] bf16 8MB
  u16* Pm   = (u16*)(ws + 134217728);          // [32][32][64][64] bf16 8MB

  prep_inputs<<<16640, 256, 0, stream>>>(x, W, gb, xb, Wb);
  gemm_bf16_btn<<<512, 512, 0, stream>>>(xb, Wb, qb, kb, vb);
  chunk_prep<<<1024, 256, 0, stream>>>(qb, kb, gb, gp, Tm, Pm);
  chunk_scan<<<256, 512, 0, stream>>>(qb, kb, vb, gp, Tm, Pm, st0, out);
}

// Round 12
// 336.655 us; speedup vs baseline: 1.0227x; 1.0227x over previous
//
#include <hip/hip_runtime.h>
#include <hip/hip_bf16.h>
#include <cstdint>

// Problem constants (B=2, T=2048, NH=16, HD=128, VD=256)
// KD=2048, VDIM=4096, proj cols: [0,2048)=q, [2048,4096)=k, [4096,8192)=v,
// [8192,8208)=g, [8208,8224)=beta.
//
// Chunked WY delta rule: per chunk of C=64 (per seq=b*16+n):
//   G_t = prod g, L_t = cumsum log g
//   A[s,r] = b_s exp(L_s-L_r)(k_s.k_r)  (r<s)       N = -A
//   T = (I+A)^{-1} = Prod_{j=0..5}(I+N^{2^j})       (nilpotent Neumann)
//   P[t,s] = exp(L_t-L_s)(q_t.k_s)  (s<=t)
//   M = K S0^T ; Mq = Q S0^T
//   U = T (diag(b)V - diag(bG) M)
//   O = diag(G) Mq + P U
//   S_C = G_C S0 + U^T diag(G_C/G_s) K
//
// LDS swizzle convention (G4 fix; both-sides-or-neither, rule 21):
//   128-u16-row tile: elem (r,c) at r*128 + (((c>>3)^(r&7))<<3) + (c&7)
//   64-u16-row tile:  elem (r,c) at r*64  + (((c>>3)^(r&7))<<3) + (c&7)
//   32-u16-row tile:  elem (r,c) at r*32  + (((c>>3)^((r>>2)&3))<<3) + (c&7)
//   gll16-staged tiles keep LINEAR dest; inverse permutation applied on the
//   per-lane GLOBAL source address. VALU-written tiles swizzle the address.
//
// GEMM note (r9 post-mortem): controlled experiments showed the GEMM's
// ~155us is set by its 8-barrier lockstep skeleton, NOT by bank conflicts
// (1.26e7 vs 0: neutral), L2 over-fetch (276 vs 99MB: neutral), or read
// balance (r2/r9). Keeping the best-measured r1-skeleton variant.
// chunk_scan note (r11): T5 setprio + staging rebalance = noise -> the
// scan is at its 4-phase barrier-rendezvous floor (r10 config is best).

typedef __attribute__((ext_vector_type(8))) short short8;
typedef __attribute__((ext_vector_type(4))) float f32x4;
typedef unsigned short u16;

using as1_void = __attribute__((address_space(1))) void;
using as3_void = __attribute__((address_space(3))) void;

__device__ __forceinline__ void gll16(const void* g, void* l) {
  // async global->LDS, 16B/lane; LDS dest = wave-uniform base + lane*16
  __builtin_amdgcn_global_load_lds((const as1_void*)g, (as3_void*)l, 16, 0, 0);
}

__device__ __forceinline__ u16 bf16_rne(float f) {
  union { float f; uint32_t u; } x; x.f = f;
  uint32_t u = x.u;
  return (u16)((u + 0x7fffu + ((u >> 16) & 1u)) >> 16);
}
__device__ __forceinline__ float bf2f(u16 v) {
  union { uint32_t u; float f; } x; x.u = (uint32_t)v << 16;
  return x.f;
}

// lgkm-only barrier: LDS producer->consumer sync without draining vmcnt
#define LGKM_BAR() do {                                      \
    asm volatile("s_waitcnt lgkmcnt(0)" ::: "memory");       \
    __builtin_amdgcn_s_barrier();                            \
    __builtin_amdgcn_sched_barrier(0);                       \
  } while (0)

#define SCHED_FENCE() __builtin_amdgcn_sched_barrier(0)
#define HW_BAR() __builtin_amdgcn_s_barrier()
#define LGKM0() asm volatile("s_waitcnt lgkmcnt(0)" ::: "memory")
#define VMCNT(n) asm volatile("s_waitcnt vmcnt(" #n ")" ::: "memory")

// ---------------- fused: W fp32->bf16 cvt  ||  gate projection ----------
// Independent workloads (cvt: HBM-bound; gate: L2/VALU-bound) run in one
// launch: blocks [0,256) = gate (4 rows/wave), blocks [256,16640) = cvt.
__global__ __launch_bounds__(256, 1) void prep_inputs(const float* __restrict__ x,
                                                      const float* __restrict__ W,
                                                      float* __restrict__ gbuf,
                                                      u16* __restrict__ xb,
                                                      u16* __restrict__ Wb) {
  if (blockIdx.x >= 256) {
    // ---- cvt path: W rows 0..8191 -> bf16 (4 floats/thread) ----
    int i = (blockIdx.x - 256) * 256 + threadIdx.x;  // < 4194304
    float4 v = ((const float4*)W)[i];
    ushort4 o;
    o.x = bf16_rne(v.x); o.y = bf16_rne(v.y);
    o.z = bf16_rne(v.z); o.w = bf16_rne(v.w);
    ((ushort4*)Wb)[i] = o;
    return;
  }
  // ---- gate path: 4 rows per wave; also emits bf16 x ----
  const int w = threadIdx.x >> 6, lane = threadIdx.x & 63;
  const int r0 = (blockIdx.x * 4 + w) * 4;  // 4 consecutive rows per wave
  const float* xr = x + (size_t)r0 * 2048 + lane * 32;
  float4 xv[4][8];
#pragma unroll
  for (int i = 0; i < 4; ++i)
#pragma unroll
    for (int j = 0; j < 8; ++j)
      xv[i][j] = ((const float4*)(xr + (size_t)i * 2048))[j];
  // bf16 x emit
#pragma unroll
  for (int i = 0; i < 4; ++i) {
    u16* xrow = xb + (size_t)(r0 + i) * 2048 + lane * 32;
#pragma unroll
    for (int j = 0; j < 8; ++j) {
      ushort4 o;
      o.x = bf16_rne(xv[i][j].x); o.y = bf16_rne(xv[i][j].y);
      o.z = bf16_rne(xv[i][j].z); o.w = bf16_rne(xv[i][j].w);
      ((ushort4*)xrow)[j] = o;
    }
  }
  for (int col = 0; col < 32; ++col) {
    const float* wp = W + (size_t)(8192 + col) * 2048 + lane * 32;
    float4 wv[8];
#pragma unroll
    for (int j = 0; j < 8; ++j) wv[j] = ((const float4*)wp)[j];
    float d[4] = {0.f, 0.f, 0.f, 0.f};
#pragma unroll
    for (int i = 0; i < 4; ++i)
#pragma unroll
      for (int j = 0; j < 8; ++j)
        d[i] += xv[i][j].x * wv[j].x + xv[i][j].y * wv[j].y +
                xv[i][j].z * wv[j].z + xv[i][j].w * wv[j].w;
#pragma unroll
    for (int i = 0; i < 4; ++i) {
      d[i] += __shfl_xor(d[i], 1);  d[i] += __shfl_xor(d[i], 2);
      d[i] += __shfl_xor(d[i], 4);  d[i] += __shfl_xor(d[i], 8);
      d[i] += __shfl_xor(d[i], 16); d[i] += __shfl_xor(d[i], 32);
    }
    if (lane == 0) {
#pragma unroll
      for (int i = 0; i < 4; ++i) {
        int rv = r0 + i, b = rv >> 11, t = rv & 2047;
        float s = 1.f / (1.f + __expf(-d[i]));
        gbuf[((size_t)(b * 16 + (col & 15)) * 2048 + t) * 2 + (col >> 4)] = s;
      }
    }
  }
}

// ---------------- 256^2 8-phase bf16 MFMA GEMM + fused q/k l2norm ----------
// (r8-measured version: r1 skeleton + st-style swizzle + XCD-bijective map)
__global__ __launch_bounds__(512, 2) void gemm_bf16_btn(const u16* __restrict__ A,
                                                        const u16* __restrict__ B,
                                                        u16* __restrict__ qb,
                                                        u16* __restrict__ kb,
                                                        u16* __restrict__ vb) {
  __shared__ __align__(16) u16 As[2][16384];
  __shared__ __align__(16) u16 Bs[2][16384];
  __shared__ float nrm[2][4][128];  // [wr][wc][row] partial sums (epilogue)

  const int tid = threadIdx.x;
  const int wid = tid >> 6, lane = tid & 63;
  const int lr = lane & 15, lk = lane >> 4;
  const int wr = wid >> 2, wc = wid & 3;

  // XCD-bijective swizzle: 512 wg, 8 XCDs, 64 wg chunks = 2 bm x 32 bn
  const int wg = ((blockIdx.x & 7) << 6) | (blockIdx.x >> 3);
  const int bm = wg >> 5, bn = wg & 31;

  const int e8s = (tid & 7) ^ (((tid >> 3) & 1) << 2) ^ (((tid >> 5) & 1) << 1);
  const int srow = tid >> 3;  // 0..63 within one 8KB call
  const u16* Agb = A + (size_t)(bm * 256 + srow) * 2048 + e8s * 8;
  const u16* Bgb = B + (size_t)(bn * 256 + srow) * 2048 + e8s * 8;

  const int kkx = lr & 1;
  const int lkp = lk ^ (((lr >> 2) & 1) << 1);
  const int aOff0 = (wr * 128 + lr) * 64 + kkx * 32 + lkp * 8;
  const int aOff1 = (wr * 128 + lr) * 64 + (1 ^ kkx) * 32 + lkp * 8;
  const int bOff0 = (wc * 64 + lr) * 64 + kkx * 32 + lkp * 8;
  const int bOff1 = (wc * 64 + lr) * 64 + (1 ^ kkx) * 32 + lkp * 8;

  auto stageA = [&](int bf, int kt, int h) {
    const u16* s = Agb + (size_t)(h * 128) * 2048 + kt * 64;
    u16* d = &As[bf][h * 8192 + wid * 512];
    gll16(s, d);
    gll16(s + (size_t)64 * 2048, d + 4096);
  };
  auto stageB = [&](int bf, int kt, int h) {
    const u16* s = Bgb + (size_t)(h * 128) * 2048 + kt * 64;
    u16* d = &Bs[bf][h * 8192 + wid * 512];
    gll16(s, d);
    gll16(s + (size_t)64 * 2048, d + 4096);
  };

  f32x4 acc[8][4] = {};

  stageA(0, 0, 0); stageA(0, 0, 1);
  stageB(0, 0, 0); stageB(0, 0, 1);
  stageA(1, 1, 0); stageA(1, 1, 1);
  stageB(1, 1, 0);
  VMCNT(6);
  SCHED_FENCE();
  HW_BAR();

#define QUAD(M0, N0)                                                          \
  do {                                                                        \
    __builtin_amdgcn_s_setprio(1);                                            \
    _Pragma("unroll")                                                         \
    for (int m_ = 0; m_ < 4; ++m_)                                            \
      _Pragma("unroll")                                                       \
      for (int n_ = 0; n_ < 2; ++n_) {                                        \
        acc[M0 + m_][N0 + n_] = __builtin_amdgcn_mfma_f32_16x16x32_bf16(      \
            a[M0 + m_][0], b[N0 + n_][0], acc[M0 + m_][N0 + n_], 0, 0, 0);    \
        acc[M0 + m_][N0 + n_] = __builtin_amdgcn_mfma_f32_16x16x32_bf16(      \
            a[M0 + m_][1], b[N0 + n_][1], acc[M0 + m_][N0 + n_], 0, 0, 0);    \
      }                                                                       \
    __builtin_amdgcn_s_setprio(0);                                            \
  } while (0)

  for (int kt = 0; kt < 32; ++kt) {
    const int bf = kt & 1;
    const u16* pA0 = &As[bf][aOff0];
    const u16* pA1 = &As[bf][aOff1];
    const u16* pB0 = &Bs[bf][bOff0];
    const u16* pB1 = &Bs[bf][bOff1];
    short8 a[8][2], b[4][2];

#pragma unroll
    for (int m = 0; m < 8; ++m) {
      a[m][0] = *(const short8*)(pA0 + m * 1024);
      a[m][1] = *(const short8*)(pA1 + m * 1024);
    }
#pragma unroll
    for (int n = 0; n < 2; ++n) {
      b[n][0] = *(const short8*)(pB0 + n * 1024);
      b[n][1] = *(const short8*)(pB1 + n * 1024);
    }
    SCHED_FENCE();
    if (kt < 31) stageB((kt + 1) & 1, kt + 1, 1);
    SCHED_FENCE(); HW_BAR(); LGKM0(); SCHED_FENCE();
    QUAD(0, 0);
    SCHED_FENCE(); HW_BAR();

#pragma unroll
    for (int n = 2; n < 4; ++n) {
      b[n][0] = *(const short8*)(pB0 + n * 1024);
      b[n][1] = *(const short8*)(pB1 + n * 1024);
    }
    SCHED_FENCE();
    if (kt < 30) stageA(bf, kt + 2, 0);
    SCHED_FENCE(); HW_BAR(); LGKM0(); SCHED_FENCE();
    QUAD(0, 2);
    SCHED_FENCE(); HW_BAR();

    if (kt < 30) stageA(bf, kt + 2, 1);
    SCHED_FENCE(); HW_BAR(); SCHED_FENCE();
    QUAD(4, 0);
    SCHED_FENCE(); HW_BAR();

    if (kt < 30) stageB(bf, kt + 2, 0);
    SCHED_FENCE(); HW_BAR(); SCHED_FENCE();
    QUAD(4, 2);
    SCHED_FENCE();
    if (kt < 30) { VMCNT(6); } else if (kt == 30) { VMCNT(0); }
    SCHED_FENCE(); HW_BAR();
  }
#undef QUAD

  // ---- epilogue: C/D layout col = lane&15, row = (lane>>4)*4 + reg ----
  if (bn < 16) {
    // q/k block: fused l2norm (same bf16-rounded values as two-pass version).
#pragma unroll
    for (int m = 0; m < 8; ++m)
#pragma unroll
      for (int r = 0; r < 4; ++r) {
        float s = 0.f;
#pragma unroll
        for (int nn = 0; nn < 4; ++nn) {
          float v = bf2f(bf16_rne(acc[m][nn][r]));
          s += v * v;
        }
        s += __shfl_xor(s, 1); s += __shfl_xor(s, 2);
        s += __shfl_xor(s, 4); s += __shfl_xor(s, 8);
        if (lr == 0) nrm[wr][wc][m * 16 + lk * 4 + r] = s;
      }
    __syncthreads();
#pragma unroll
    for (int m = 0; m < 8; ++m)
#pragma unroll
      for (int r = 0; r < 4; ++r) {
        int rloc = m * 16 + lk * 4 + r;
        float ss = nrm[wr][wc][rloc] + nrm[wr][wc ^ 1][rloc];
        float sc = 1.f / fmaxf(sqrtf(ss), 1e-12f);
        int row = bm * 256 + wr * 128 + rloc;
        int bb = row >> 11, tt = row & 2047;
#pragma unroll
        for (int nn = 0; nn < 4; ++nn) {
          int col = bn * 256 + wc * 64 + nn * 16 + lr;
          int head = (col >> 7) & 15;
          int h = col & 127;
          u16 val = bf16_rne(bf2f(bf16_rne(acc[m][nn][r])) * sc);
          u16* dst = (col < 2048) ? qb : kb;
          dst[((size_t)(bb * 16 + head) * 2048 + tt) * 128 + h] = val;
        }
      }
  } else {
    // v block: plain store
#pragma unroll
    for (int m = 0; m < 8; ++m)
#pragma unroll
      for (int nn = 0; nn < 4; ++nn)
#pragma unroll
        for (int r = 0; r < 4; ++r) {
          int row = bm * 256 + wr * 128 + m * 16 + lk * 4 + r;
          int col = bn * 256 + wc * 64 + nn * 16 + lr;
          int bb = row >> 11, tt = row & 2047;
          u16 val = bf16_rne(acc[m][nn][r]);
          int vh = col - 4096;
          vb[((size_t)(bb * 16 + (vh >> 8)) * 2048 + tt) * 256 + (vh & 255)] = val;
        }
  }
}

// ---------------- chunk_prep: per (seq,chunk) T,P,gatepack (swizzled LDS) ---
__global__ __launch_bounds__(256) void chunk_prep(const u16* __restrict__ qb,
                                                  const u16* __restrict__ kb,
                                                  const float* __restrict__ gbuf,
                                                  float* __restrict__ gp,
                                                  u16* __restrict__ Tm,
                                                  u16* __restrict__ Pm) {
  __shared__ u16 Kc[64 * 128];
  __shared__ u16 Qc[64 * 128];
  __shared__ u16 Nn[64 * 64];
  __shared__ u16 NT[64 * 64];
  __shared__ u16 Tt[64 * 64];
  __shared__ u16 TTt[64 * 64];
  __shared__ float gl[256];
  __shared__ float Lw[64];
  __shared__ float bw[64];

  const int bid = blockIdx.x;
  const int seq = bid >> 5, c = bid & 31;
  const int t0 = c * 64;
  const int tid = threadIdx.x;
  const int w = tid >> 6, lane = tid & 63;
  const int lr = lane & 15, lk = lane >> 4;
  const int lr7 = lr & 7;

  {
    const int rowo = lane >> 4;
    const int c8e = (lane & 15) ^ rowo;
    const int c8o = (lane & 15) ^ (4 | rowo);
    if (w == 0) {
      const u16* se = kb + ((size_t)seq * 2048 + t0 + rowo) * 128 + c8e * 8;
      const u16* so = kb + ((size_t)seq * 2048 + t0 + rowo) * 128 + c8o * 8;
#pragma unroll
      for (int i = 0; i < 16; ++i)
        gll16(((i & 1) ? so : se) + (size_t)i * 512, &Kc[i * 512]);
    } else if (w == 1) {
      const u16* se = qb + ((size_t)seq * 2048 + t0 + rowo) * 128 + c8e * 8;
      const u16* so = qb + ((size_t)seq * 2048 + t0 + rowo) * 128 + c8o * 8;
#pragma unroll
      for (int i = 0; i < 16; ++i)
        gll16(((i & 1) ? so : se) + (size_t)i * 512, &Qc[i * 512]);
    } else if (w == 2) {
      gll16(gbuf + (size_t)seq * 4096 + c * 128 + lane * 4, &gl[0]);
    }
  }
  __syncthreads();

  if (w == 0) {
    float g = gl[2 * lane], b = gl[2 * lane + 1];
    float lg = __logf(g);
#pragma unroll
    for (int d = 1; d < 64; d <<= 1) {
      float y = __shfl_up(lg, d);
      if (lane >= d) lg += y;
    }
    Lw[lane] = lg;
    bw[lane] = b;
    float G = __expf(lg);
    float L63 = __shfl(lg, 63);
    float wgt = __expf(L63 - lg);
    float* gpo = gp + ((size_t)seq * 32 + c) * 256;
    gpo[lane] = b;
    gpo[64 + lane] = b * G;
    gpo[128 + lane] = G;
    gpo[192 + lane] = wgt;
  }
  __syncthreads();

  f32x4 kkacc[4] = {}, qkacc[4] = {};
#pragma unroll
  for (int ct = 0; ct < 4; ++ct)
#pragma unroll
    for (int k0 = 0; k0 < 4; ++k0) {
      const int sl = ((k0 * 4 + lk) ^ lr7) << 3;
      short8 bfr = *(const short8*)&Kc[(ct * 16 + lr) * 128 + sl];
      short8 afk = *(const short8*)&Kc[(w * 16 + lr) * 128 + sl];
      short8 afq = *(const short8*)&Qc[(w * 16 + lr) * 128 + sl];
      kkacc[ct] = __builtin_amdgcn_mfma_f32_16x16x32_bf16(afk, bfr, kkacc[ct], 0, 0, 0);
      qkacc[ct] = __builtin_amdgcn_mfma_f32_16x16x32_bf16(afq, bfr, qkacc[ct], 0, 0, 0);
    }
  u16* Pout = Pm + ((size_t)seq * 32 + c) * 4096;
#pragma unroll
  for (int ct = 0; ct < 4; ++ct)
#pragma unroll
    for (int r = 0; r < 4; ++r) {
      int s = w * 16 + lk * 4 + r;
      int cc = ct * 16 + lr;
      int iA = s * 64 + ((((ct * 2 + (lr >> 3)) ^ (s & 7)) << 3)) + lr7;
      int iB = cc * 64 + ((((s >> 3) ^ lr7) << 3)) + (s & 7);
      u16 nv = 0;
      if (cc < s)
        nv = bf16_rne(-(bw[s] * __expf(Lw[s] - Lw[cc]) * kkacc[ct][r]));
      Nn[iA] = nv;
      NT[iB] = nv;
      u16 tv = (cc == s) ? (u16)0x3F80 : nv;
      Tt[iA] = tv;
      TTt[iB] = tv;
      u16 pv = 0;
      if (cc <= s)
        pv = bf16_rne(__expf(Lw[s] - Lw[cc]) * qkacc[ct][r]);
      Pout[s * 64 + cc] = pv;
    }
  __syncthreads();

  u16* Tout = Tm + ((size_t)seq * 32 + c) * 4096;
#pragma unroll 1
  for (int j = 0; j < 5; ++j) {
    f32x4 acc2[4] = {};
#pragma unroll
    for (int ct = 0; ct < 4; ++ct)
#pragma unroll
      for (int k0 = 0; k0 < 2; ++k0) {
        const int sl = ((k0 * 4 + lk) ^ lr7) << 3;
        short8 af = *(const short8*)&Nn[(w * 16 + lr) * 64 + sl];
        short8 bfr = *(const short8*)&NT[(ct * 16 + lr) * 64 + sl];
        acc2[ct] = __builtin_amdgcn_mfma_f32_16x16x32_bf16(af, bfr, acc2[ct], 0, 0, 0);
      }
    __syncthreads();
#pragma unroll
    for (int ct = 0; ct < 4; ++ct)
#pragma unroll
      for (int r = 0; r < 4; ++r) {
        int s = w * 16 + lk * 4 + r, cc = ct * 16 + lr;
        int iA = s * 64 + ((((ct * 2 + (lr >> 3)) ^ (s & 7)) << 3)) + lr7;
        int iB = cc * 64 + ((((s >> 3) ^ lr7) << 3)) + (s & 7);
        u16 v = bf16_rne(acc2[ct][r]);
        Nn[iA] = v;
        NT[iB] = v;
      }
    __syncthreads();
    f32x4 acc3[4];
#pragma unroll
    for (int ct = 0; ct < 4; ++ct)
#pragma unroll
      for (int r = 0; r < 4; ++r) {
        int a = w * 16 + lk * 4 + r;
        acc3[ct][r] = bf2f(Tt[a * 64 + ((((ct * 2 + (lr >> 3)) ^ (a & 7)) << 3)) + lr7]);
      }
#pragma unroll
    for (int ct = 0; ct < 4; ++ct)
#pragma unroll
      for (int k0 = 0; k0 < 2; ++k0) {
        const int sl = ((k0 * 4 + lk) ^ lr7) << 3;
        short8 af = *(const short8*)&Nn[(w * 16 + lr) * 64 + sl];
        short8 bfr = *(const short8*)&TTt[(ct * 16 + lr) * 64 + sl];
        acc3[ct] = __builtin_amdgcn_mfma_f32_16x16x32_bf16(af, bfr, acc3[ct], 0, 0, 0);
      }
    __syncthreads();
    if (j < 4) {
#pragma unroll
      for (int ct = 0; ct < 4; ++ct)
#pragma unroll
        for (int r = 0; r < 4; ++r) {
          int s = w * 16 + lk * 4 + r, cc = ct * 16 + lr;
          int iA = s * 64 + ((((ct * 2 + (lr >> 3)) ^ (s & 7)) << 3)) + lr7;
          int iB = cc * 64 + ((((s >> 3) ^ lr7) << 3)) + (s & 7);
          u16 v = bf16_rne(acc3[ct][r]);
          Tt[iA] = v;
          TTt[iB] = v;
        }
      __syncthreads();
    } else {
#pragma unroll
      for (int ct = 0; ct < 4; ++ct)
#pragma unroll
        for (int r = 0; r < 4; ++r) {
          int s = w * 16 + lk * 4 + r, cc = ct * 16 + lr;
          Tout[s * 64 + cc] = bf16_rne(acc3[ct][r]);
        }
    }
  }
}

// ---------------- chunk_scan: serial over 32 chunks, MFMA, 8 waves ----------
// 512 thr (r6 structure + KTw build in phase C on waves 4-7).
__global__ __launch_bounds__(512) void chunk_scan(const u16* __restrict__ qb,
                                                  const u16* __restrict__ kb,
                                                  const u16* __restrict__ vb,
                                                  const float* __restrict__ gp,
                                                  const u16* __restrict__ Tm,
                                                  const u16* __restrict__ Pm,
                                                  const float* __restrict__ st0,
                                                  float* __restrict__ out) {
  __shared__ u16 Kc[2][64 * 128];
  __shared__ u16 Qc[2][64 * 128];
  __shared__ u16 Vc[2][64 * 32];
  __shared__ u16 Tc[2][64 * 64];
  __shared__ u16 Pc[2][64 * 64];
  __shared__ float gpl[2][256];
  __shared__ u16 KTw[128 * 64];
  __shared__ u16 Sb[32 * 128];
  __shared__ u16 RT[32 * 64];
  __shared__ u16 UT[32 * 64];

  const int bid = blockIdx.x;
  const int shard = bid >> 5, seq = bid & 31;
  const int vs0 = shard * 32;
  const int b = seq >> 4, n = seq & 15;
  const int tid = threadIdx.x;
  const int w = tid >> 6, lane = tid & 63;
  const int lr = lane & 15, lk = lane >> 4;
  const int lr7 = lr & 7;
  const int w3 = w & 3;
  const int vt = w & 1, hgb = (w >> 1) * 2;  // state: 2 h-tiles per wave

  const u16* kbase = kb + (size_t)seq * 2048 * 128;
  const u16* qbase = qb + (size_t)seq * 2048 * 128;
  const u16* vbase = vb + (size_t)seq * 2048 * 256 + vs0;
  const float* gpbase = gp + (size_t)seq * 32 * 256;
  const u16* Tbase = Tm + (size_t)seq * 32 * 4096;
  const u16* Pbase = Pm + (size_t)seq * 32 * 4096;

  // staging source pre-swizzle constants
  const int rowo = lane >> 4;
  const int c8e = (lane & 15) ^ rowo;          // even 4-row group (128-col tiles)
  const int c8o = (lane & 15) ^ (4 | rowo);    // odd 4-row group
  const int tp8 = (lane & 7) ^ (lane >> 3);    // T/P 64-col tiles (i-indep)
  const int vc8 = (lane & 3) ^ (lane >> 4);    // V 32-col tile (i-indep)

  auto stage = [&](int sb, int c) {
    const int t0 = c * 64;
    if (w == 0 || w == 4) {
      const int i0 = (w == 0) ? 0 : 8;
      const u16* se = kbase + (size_t)(t0 + rowo) * 128 + c8e * 8;
      const u16* so = kbase + (size_t)(t0 + rowo) * 128 + c8o * 8;
#pragma unroll
      for (int i = 0; i < 8; ++i) {
        const int ii = i0 + i;
        gll16(((ii & 1) ? so : se) + (size_t)ii * 512, &Kc[sb][ii * 512]);
      }
    } else if (w == 1 || w == 5) {
      const int i0 = (w == 1) ? 0 : 8;
      const u16* se = qbase + (size_t)(t0 + rowo) * 128 + c8e * 8;
      const u16* so = qbase + (size_t)(t0 + rowo) * 128 + c8o * 8;
#pragma unroll
      for (int i = 0; i < 8; ++i) {
        const int ii = i0 + i;
        gll16(((ii & 1) ? so : se) + (size_t)ii * 512, &Qc[sb][ii * 512]);
      }
    } else if (w == 2) {
      const u16* srcT = Tbase + (size_t)c * 4096 + (lane >> 3) * 64 + tp8 * 8;
#pragma unroll
      for (int i = 0; i < 8; ++i) gll16(srcT + (size_t)i * 512, &Tc[sb][i * 512]);
    } else if (w == 6) {
      const u16* srcP = Pbase + (size_t)c * 4096 + (lane >> 3) * 64 + tp8 * 8;
#pragma unroll
      for (int i = 0; i < 8; ++i) gll16(srcP + (size_t)i * 512, &Pc[sb][i * 512]);
    } else if (w == 3) {
      const u16* src = vbase + (size_t)(t0 + (lane >> 2)) * 256 + vc8 * 8;
#pragma unroll
      for (int i = 0; i < 4; ++i) gll16(src + (size_t)i * 4096, &Vc[sb][i * 512]);
    } else {  // w == 7
      gll16(gpbase + (size_t)c * 256 + lane * 4, &gpl[sb][0]);
    }
  };

  // state init: wave owns rows vt*16.. (v) x h-tiles hgb..hgb+1
  f32x4 s_acc[2];
  {
    const float* s0p = st0 + ((size_t)seq * 256 + vs0) * 128;
#pragma unroll
    for (int ht = 0; ht < 2; ++ht)
#pragma unroll
      for (int r = 0; r < 4; ++r)
        s_acc[ht][r] = s0p[(size_t)(vt * 16 + lk * 4 + r) * 128 + (hgb + ht) * 16 + lr];
  }
  stage(0, 0);
  __syncthreads();

  for (int c = 0; c < 32; ++c) {
    const int buf = c & 1;
    const int t0 = c * 64;

    // ---- phase A: prefetch next chunk; build Sb (bf16 state) ----
    stage(buf ^ 1, (c < 31) ? c + 1 : 31);
#pragma unroll
    for (int ht = 0; ht < 2; ++ht)
#pragma unroll
      for (int r = 0; r < 4; ++r) {
        int row = vt * 16 + lk * 4 + r;
        int c8 = (hgb + ht) * 2 + (lr >> 3);
        Sb[row * 128 + ((c8 ^ (row & 7)) << 3) + lr7] = bf16_rne(s_acc[ht][r]);
      }
    LGKM_BAR();

    // ---- phase B: waves 0-3: M = K Sb^T -> RT ; waves 4-7: Mq = Q Sb^T ----
    f32x4 mm_acc[2] = {};
    if (w < 4) {
#pragma unroll
      for (int ct = 0; ct < 2; ++ct)
#pragma unroll
        for (int k0 = 0; k0 < 4; ++k0) {
          const int sl = ((k0 * 4 + lk) ^ lr7) << 3;
          short8 bfr = *(const short8*)&Sb[(ct * 16 + lr) * 128 + sl];
          short8 afk = *(const short8*)&Kc[buf][(w3 * 16 + lr) * 128 + sl];
          mm_acc[ct] = __builtin_amdgcn_mfma_f32_16x16x32_bf16(afk, bfr, mm_acc[ct], 0, 0, 0);
        }
#pragma unroll
      for (int ct = 0; ct < 2; ++ct)
#pragma unroll
        for (int r = 0; r < 4; ++r) {
          int t = w3 * 16 + lk * 4 + r;
          int j2 = ct * 16 + lr;
          float bt = gpl[buf][t], bG = gpl[buf][64 + t];
          float vv = bf2f(Vc[buf][t * 32 + ((((ct * 2 + (lr >> 3)) ^ lk)) << 3) + lr7]);
          float rv = bt * vv - bG * mm_acc[ct][r];
          RT[j2 * 64 + (((t >> 3) ^ lr7) << 3) + (t & 7)] = bf16_rne(rv);
        }
    } else {
#pragma unroll
      for (int ct = 0; ct < 2; ++ct)
#pragma unroll
        for (int k0 = 0; k0 < 4; ++k0) {
          const int sl = ((k0 * 4 + lk) ^ lr7) << 3;
          short8 bfr = *(const short8*)&Sb[(ct * 16 + lr) * 128 + sl];
          short8 afq = *(const short8*)&Qc[buf][(w3 * 16 + lr) * 128 + sl];
          mm_acc[ct] = __builtin_amdgcn_mfma_f32_16x16x32_bf16(afq, bfr, mm_acc[ct], 0, 0, 0);
        }
    }
    LGKM_BAR();

    // ---- phase C: waves 0-3: U = T R -> UT ; waves 4-7: build KTw ----
    if (w < 4) {
      f32x4 u_acc[2] = {};
#pragma unroll
      for (int ct = 0; ct < 2; ++ct)
#pragma unroll
        for (int k0 = 0; k0 < 2; ++k0) {
          const int sl = ((k0 * 4 + lk) ^ lr7) << 3;
          short8 af = *(const short8*)&Tc[buf][(w3 * 16 + lr) * 64 + sl];
          short8 bfr = *(const short8*)&RT[(ct * 16 + lr) * 64 + sl];
          u_acc[ct] = __builtin_amdgcn_mfma_f32_16x16x32_bf16(af, bfr, u_acc[ct], 0, 0, 0);
        }
#pragma unroll
      for (int ct = 0; ct < 2; ++ct)
#pragma unroll
        for (int r = 0; r < 4; ++r) {
          int s2 = w3 * 16 + lk * 4 + r;
          int j2 = ct * 16 + lr;
          UT[j2 * 64 + (((s2 >> 3) ^ lr7) << 3) + (s2 & 7)] = bf16_rne(u_acc[ct][r]);
        }
    } else {
      // KTw[h][s] = (G_C/G_s) * K[s][h], swizzled 64-u16-row layout.
      const int s = (tid - 256) >> 2;  // 0..63
      const int cb0 = (tid & 3) * 4;   // col slots cb0..cb0+3 (h = slot*8+j)
      const float ws = gpl[buf][192 + s];
#pragma unroll
      for (int q = 0; q < 4; ++q) {
        const int cb = cb0 + q;
        short8 kv = *(const short8*)&Kc[buf][s * 128 + ((cb ^ (s & 7)) << 3)];
#pragma unroll
        for (int j = 0; j < 8; ++j) {
          int row = cb * 8 + j;
          KTw[row * 64 + (((s >> 3) ^ (j & 7)) << 3) + (s & 7)] =
              bf16_rne(ws * bf2f((u16)kv[j]));
        }
      }
    }
    LGKM_BAR();

    // ---- phase D: all: S = G_C S + U^T KTw ; waves 4-7: O -> out ----
    {
      const float Gc = gpl[buf][128 + 63];
#pragma unroll
      for (int ht = 0; ht < 2; ++ht) {
        s_acc[ht][0] *= Gc; s_acc[ht][1] *= Gc;
        s_acc[ht][2] *= Gc; s_acc[ht][3] *= Gc;
      }
#pragma unroll
      for (int ht = 0; ht < 2; ++ht)
#pragma unroll
        for (int k0 = 0; k0 < 2; ++k0) {
          const int sl = ((k0 * 4 + lk) ^ lr7) << 3;
          short8 af = *(const short8*)&UT[(vt * 16 + lr) * 64 + sl];
          short8 bfr = *(const short8*)&KTw[((hgb + ht) * 16 + lr) * 64 + sl];
          s_acc[ht] = __builtin_amdgcn_mfma_f32_16x16x32_bf16(af, bfr, s_acc[ht], 0, 0, 0);
        }
    }
    if (w >= 4) {
      f32x4 o_acc[2];
#pragma unroll
      for (int ct = 0; ct < 2; ++ct)
#pragma unroll
        for (int r = 0; r < 4; ++r) {
          int t = w3 * 16 + lk * 4 + r;
          o_acc[ct][r] = gpl[buf][128 + t] * mm_acc[ct][r];
        }
#pragma unroll
      for (int ct = 0; ct < 2; ++ct)
#pragma unroll
        for (int k0 = 0; k0 < 2; ++k0) {
          const int sl = ((k0 * 4 + lk) ^ lr7) << 3;
          short8 af = *(const short8*)&Pc[buf][(w3 * 16 + lr) * 64 + sl];
          short8 bfr = *(const short8*)&UT[(ct * 16 + lr) * 64 + sl];
          o_acc[ct] = __builtin_amdgcn_mfma_f32_16x16x32_bf16(af, bfr, o_acc[ct], 0, 0, 0);
        }
#pragma unroll
      for (int ct = 0; ct < 2; ++ct)
#pragma unroll
        for (int r = 0; r < 4; ++r) {
          int t = w3 * 16 + lk * 4 + r;
          int j2 = ct * 16 + lr;
          out[(((size_t)b * 2048 + t0 + t) * 16 + n) * 256 + vs0 + j2] = o_acc[ct][r];
        }
    }
    __syncthreads();  // drains vmcnt: next chunk staged; LDS reads done
  }
}

extern "C" void kernel_launch(void* const* d_in, const int* in_sizes, int n_in,
                              void* d_out, int out_size, void* d_ws, size_t ws_size,
                              hipStream_t stream) {
  const float* x = (const float*)d_in[0];    // [2,2048,2048]
  const float* W = (const float*)d_in[1];    // [8224,2048]
  const float* st0 = (const float*)d_in[2];  // [2,16,256,128] (zeros)
  float* out = (float*)d_out;                // [2,2048,16,256]
  char* ws = (char*)d_ws;

  u16* xb   = (u16*)ws;                        // 16 MB bf16 x
  u16* Wb   = (u16*)(ws + 16777216);           // 32 MB bf16 W
  u16* qb   = (u16*)(ws + 50331648);           // [32][2048][128] bf16 16MB
  u16* kb   = (u16*)(ws + 67108864);           // [32][2048][128] bf16 16MB
  u16* vb   = (u16*)(ws + 83886080);           // [32][2048][256] bf16 32MB
  float* gb = (float*)(ws + 117440512);        // [32][2048][2] f32 512KB (+slack)
  float* gp = (float*)(ws + 123731968);        // [32][32][4][64] f32 1MB
  u16* Tm   = (u16*)(ws + 125829120);          // [32][32][64][64] bf16 8MB
  u16* Pm   = (u16*)(ws + 134217728);          // [32][32][64][64] bf16 8MB

  prep_inputs<<<16640, 256, 0, stream>>>(x, W, gb, xb, Wb);
  gemm_bf16_btn<<<512, 512, 0, stream>>>(xb, Wb, qb, kb, vb);
  chunk_prep<<<1024, 256, 0, stream>>>(qb, kb, gb, gp, Tm, Pm);
  chunk_scan<<<256, 512, 0, stream>>>(qb, kb, vb, gp, Tm, Pm, st0, out);
}